// Round 29
// baseline (35.064 us; speedup 1.0000x reference)
//
#include <hip/hip_runtime.h>
#include <hip/hip_fp16.h>

#define J_DIM 25
#define T_DIM 120
#define O_DIM 64
#define KPAD  328        // f16 per ys/Wf row; 656 B = 41*16 (b128-aligned)
#define RPB   60         // t-rows per block; halves t0 = 0, 60 -> ZERO dup phase-1 rows
#define RPW   15         // rows per wave
#define WR    19         // window rows per wave slice (RPW + 4)
#define XPADH 24         // xs row pad (halves): 48 B rows -> 16-B aligned

typedef _Float16 f16x8 __attribute__((ext_vector_type(8)));
typedef __attribute__((ext_vector_type(4))) float f32x4;

__device__ __forceinline__ unsigned h2bits(__half2 h) {
    unsigned u; __builtin_memcpy(&u, &h, 4); return u;
}
__device__ __forceinline__ __half2 bits2h(unsigned u) {
    __half2 h; __builtin_memcpy(&h, &u, 4); return h;
}
// select one of 4 half2 by q (0..3): 3 v_cndmask, no LDS, no runtime reg-indexing
__device__ __forceinline__ __half2 sel4h(int q, __half2 a, __half2 b, __half2 c, __half2 d) {
    unsigned s01 = (q & 1) ? h2bits(b) : h2bits(a);
    unsigned s23 = (q & 1) ? h2bits(d) : h2bits(c);
    return bits2h((q & 2) ? s23 : s01);
}

// ---- W (306x64 f32) -> Wf[o][k] f16, k = 18a+b; b<17: 0.5*W2[a,b]; b==17: W1[a] ----
__global__ void wprep(const float* __restrict__ W, __half* __restrict__ Wf) {
    int i = blockIdx.x * 256 + threadIdx.x;
    if (i >= O_DIM * KPAD) return;
    int o = i / KPAD, k = i % KPAD;
    int a = k / 18, b = k % 18;
    float v = 0.0f;
    if (k < 306) v = (b == 17) ? W[a * O_DIM + o] : 0.5f * W[(17 + 17 * a + b) * O_DIM + o];
    Wf[o * KPAD + k] = __float2half(v);
}

// ---- main: block = (n, j, 60-row half); 256 threads; SINGLE block barrier ----
// R25 shell (proven 33.1-33.2 us) with zero-duplication tiling: 15 rows/wave,
// t0 in {0,60}. Wave-local stage + phase-1 (wave_barrier only), one
// __syncthreads, phase 2 o-quarter with bfrag[10] register reuse.
// Lessons: no launch_bounds clamp (R6/R10); flat straight-line phases
// (R8/R9/R13); no runtime reg-array indexing (rule #20); bfrag reuse is
// load-bearing (R24/R26); R27 micro-opts neutral -> not carried.
__global__ __launch_bounds__(256, 2) void sig_mfma(
    const float* __restrict__ x, const __half* __restrict__ Wf,
    const float* __restrict__ bias, float* __restrict__ out)
{
    __shared__ __half xs[4][WR][XPADH];          // 3,648 B (per-wave 19-row slices)
    __shared__ __half ys[RPB * KPAD];            // 39,360 B  (total 43 KB -> 3 blk/CU)

    const int tid = threadIdx.x;
    const int bid = blockIdx.x;
    const int half_ = bid & 1;
    const int j = (bid >> 1) % J_DIM;
    const int n = bid / (2 * J_DIM);
    const int t0 = half_ * RPB;                  // 0 or 60 — exact tiling, no dup rows
    const int wave = tid >> 6, lane = tid & 63;
    const int l15 = lane & 15, l4 = lane >> 4;
    const int r0w = wave * RPW;                  // this wave's first row (0,15,30,45)

    // ---- wave-local stage: xs[wave][i][c] = f16 x[n,c,j,clamp(t0+r0w-2+i)] ----
    const float* xbase = x + ((size_t)(n * 16) * J_DIM + j) * T_DIM;
    #pragma unroll
    for (int k = 0; k < 5; ++k) {
        int idx = lane + k * 64;                 // 0..319; 16 ch x 19 rows = 304 used
        if (idx < 16 * WR) {
            int c = idx / WR, i = idx % WR;
            int st = min(max(t0 + r0w - 2 + i, 0), T_DIM - 1);
            xs[wave][i][c] = __float2half(xbase[(size_t)c * J_DIM * T_DIM + st]);
        }
    }
    // wave-local zero of this wave's 15 rows' pad bytes [608,656)
    // ([608,612) re-written below by the same wave's time-row store: DS in-order)
    if (lane < RPW * 3) {
        int r = lane / 3, p = lane % 3;
        *(uint4*)((char*)ys + (r0w + r) * 656 + 608 + p * 16) = uint4{0, 0, 0, 0};
    }
    __builtin_amdgcn_wave_barrier();             // program-order pin (no runtime cost)

    // ---- phase 1: thread = (rloc = lane>>2 < 15, qg = lane&3); q = qg, qg+4 ----
    // S2[a,b] = sum_w h_w[a]*p_w[b], h = (-p1, p0-p2, p1-p3, p2-p4, p3+p4)
    {
        const int rloc = lane >> 2, qg = lane & 3;
        if (rloc < RPW) {
            const int row = r0w + rloc;          // 0..59
            const int t = t0 + row;
            const int start = max(t - 2, 0), end = min(t + 3, T_DIM);
            const float inv = 1.0f / (float)(end - start - 1);
            float ptvf[5];
            #pragma unroll
            for (int w = 0; w < 5; ++w) {
                int pcw = min(max(t - 2 + w, 0), T_DIM - 1);
                ptvf[w] = (float)(pcw - start) * inv;
            }
            __half2 ptvb[5];
            #pragma unroll
            for (int w = 0; w < 5; ++w) ptvb[w] = __float2half2_rn(ptvf[w]);

            // full 16-channel window: 2 x uint4 (b128) per row, unpack to half2 regs
            __half2 xw[5][8];
            #pragma unroll
            for (int w = 0; w < 5; ++w) {
                uint4 lo = *(const uint4*)&xs[wave][rloc + w][0];
                uint4 hi = *(const uint4*)&xs[wave][rloc + w][8];
                xw[w][0] = bits2h(lo.x); xw[w][1] = bits2h(lo.y);
                xw[w][2] = bits2h(lo.z); xw[w][3] = bits2h(lo.w);
                xw[w][4] = bits2h(hi.x); xw[w][5] = bits2h(hi.y);
                xw[w][6] = bits2h(hi.z); xw[w][7] = bits2h(hi.w);
            }

            // ---------- A-pair: q = qg, a-rows {2qg, 2qg+1} ----------
            {
                __half2 pr[5];
                #pragma unroll
                for (int w = 0; w < 5; ++w)
                    pr[w] = sel4h(qg, xw[w][0], xw[w][1], xw[w][2], xw[w][3]);
                __half2 hp[5];
                hp[0] = __hneg2(pr[1]);
                hp[1] = __hsub2(pr[0], pr[2]);
                hp[2] = __hsub2(pr[1], pr[3]);
                hp[3] = __hsub2(pr[2], pr[4]);
                hp[4] = __hadd2(pr[3], pr[4]);
                __half2 h0b[5], h1b[5];
                #pragma unroll
                for (int w = 0; w < 5; ++w) {
                    h0b[w] = __low2half2(hp[w]);
                    h1b[w] = __high2half2(hp[w]);
                }
                unsigned u0[9], u1[9];
                #pragma unroll
                for (int b2 = 0; b2 < 8; ++b2) {
                    __half2 a0 = __hmul2(h0b[0], xw[0][b2]);
                    __half2 a1 = __hmul2(h1b[0], xw[0][b2]);
                    #pragma unroll
                    for (int w = 1; w < 5; ++w) {
                        a0 = __hfma2(h0b[w], xw[w][b2], a0);
                        a1 = __hfma2(h1b[w], xw[w][b2], a1);
                    }
                    u0[b2] = h2bits(a0);
                    u1[b2] = h2bits(a1);
                }
                {   // b-pair (16,17): {S2[a,16], S1[a]=p4[a]}
                    __half2 a16 = __hmul2(hp[0], ptvb[0]);
                    #pragma unroll
                    for (int w = 1; w < 5; ++w) a16 = __hfma2(hp[w], ptvb[w], a16);
                    u0[8] = h2bits(__halves2half2(__low2half(a16),  __low2half(pr[4])));
                    u1[8] = h2bits(__halves2half2(__high2half(a16), __high2half(pr[4])));
                }
                char* yr = (char*)ys + row * 656 + 72 * qg;      // rows 2qg,2qg+1
                *(uint2*)(yr +  0) = uint2{u0[0], u0[1]};
                *(uint2*)(yr +  8) = uint2{u0[2], u0[3]};
                *(uint2*)(yr + 16) = uint2{u0[4], u0[5]};
                *(uint2*)(yr + 24) = uint2{u0[6], u0[7]};
                *(uint2*)(yr + 32) = uint2{u0[8], u1[0]};
                *(uint2*)(yr + 40) = uint2{u1[1], u1[2]};
                *(uint2*)(yr + 48) = uint2{u1[3], u1[4]};
                *(uint2*)(yr + 56) = uint2{u1[5], u1[6]};
                *(uint2*)(yr + 64) = uint2{u1[7], u1[8]};
            }

            // ---------- B-pair: q = qg+4, a-rows {2qg+8, 2qg+9} ----------
            {
                __half2 pr[5];
                #pragma unroll
                for (int w = 0; w < 5; ++w)
                    pr[w] = sel4h(qg, xw[w][4], xw[w][5], xw[w][6], xw[w][7]);
                __half2 hp[5];
                hp[0] = __hneg2(pr[1]);
                hp[1] = __hsub2(pr[0], pr[2]);
                hp[2] = __hsub2(pr[1], pr[3]);
                hp[3] = __hsub2(pr[2], pr[4]);
                hp[4] = __hadd2(pr[3], pr[4]);
                __half2 h0b[5], h1b[5];
                #pragma unroll
                for (int w = 0; w < 5; ++w) {
                    h0b[w] = __low2half2(hp[w]);
                    h1b[w] = __high2half2(hp[w]);
                }
                unsigned u0[9], u1[9];
                #pragma unroll
                for (int b2 = 0; b2 < 8; ++b2) {
                    __half2 a0 = __hmul2(h0b[0], xw[0][b2]);
                    __half2 a1 = __hmul2(h1b[0], xw[0][b2]);
                    #pragma unroll
                    for (int w = 1; w < 5; ++w) {
                        a0 = __hfma2(h0b[w], xw[w][b2], a0);
                        a1 = __hfma2(h1b[w], xw[w][b2], a1);
                    }
                    u0[b2] = h2bits(a0);
                    u1[b2] = h2bits(a1);
                }
                {   // b-pair (16,17)
                    __half2 a16 = __hmul2(hp[0], ptvb[0]);
                    #pragma unroll
                    for (int w = 1; w < 5; ++w) a16 = __hfma2(hp[w], ptvb[w], a16);
                    u0[8] = h2bits(__halves2half2(__low2half(a16),  __low2half(pr[4])));
                    u1[8] = h2bits(__halves2half2(__high2half(a16), __high2half(pr[4])));
                }
                char* yr = (char*)ys + row * 656 + 72 * qg + 288;  // rows 2qg+8, 2qg+9
                *(uint2*)(yr +  0) = uint2{u0[0], u0[1]};
                *(uint2*)(yr +  8) = uint2{u0[2], u0[3]};
                *(uint2*)(yr + 16) = uint2{u0[4], u0[5]};
                *(uint2*)(yr + 24) = uint2{u0[6], u0[7]};
                *(uint2*)(yr + 32) = uint2{u0[8], u1[0]};
                *(uint2*)(yr + 40) = uint2{u1[1], u1[2]};
                *(uint2*)(yr + 48) = uint2{u1[3], u1[4]};
                *(uint2*)(yr + 56) = uint2{u1[5], u1[6]};
                *(uint2*)(yr + 64) = uint2{u1[7], u1[8]};
            }

            // ---------- time row a=16 (once per row, qg==0; same wave as pad-zero) ----------
            if (qg == 0) {
                __half2 htb[5];
                htb[0] = __float2half2_rn(-ptvf[1]);
                htb[1] = __float2half2_rn(ptvf[0] - ptvf[2]);
                htb[2] = __float2half2_rn(ptvf[1] - ptvf[3]);
                htb[3] = __float2half2_rn(ptvf[2] - ptvf[4]);
                htb[4] = __float2half2_rn(ptvf[3] + ptvf[4]);
                unsigned ut[9];
                #pragma unroll
                for (int b2 = 0; b2 < 8; ++b2) {
                    __half2 a = __hmul2(htb[0], xw[0][b2]);
                    #pragma unroll
                    for (int w = 1; w < 5; ++w) a = __hfma2(htb[w], xw[w][b2], a);
                    ut[b2] = h2bits(a);
                }
                {   // {S2[16,16], S1[16]=ptv4}
                    __half2 a = __hmul2(htb[0], ptvb[0]);
                    #pragma unroll
                    for (int w = 1; w < 5; ++w) a = __hfma2(htb[w], ptvb[w], a);
                    ut[8] = h2bits(__halves2half2(__low2half(a), __float2half(ptvf[4])));
                }
                char* yt = (char*)ys + row * 656 + 576;          // bytes [576,612)
                *(uint2*)(yt +  0) = uint2{ut[0], ut[1]};
                *(uint2*)(yt +  8) = uint2{ut[2], ut[3]};
                *(uint2*)(yt + 16) = uint2{ut[4], ut[5]};
                *(uint2*)(yt + 24) = uint2{ut[6], ut[7]};
                *(unsigned*)(yt + 32) = ut[8];
            }
        }
    }
    __syncthreads();    // the ONLY block barrier: ys complete -> phase 2

    // ---- phase 2: wave = o-quarter; B-frags loaded once; M-tiles {0,16,32,44} ----
    // tile at 44 re-reads rows 44..47 (in-bounds) and duplicate-stores t rows
    // 44..47 of this half with identical values (same ys rows) — benign.
    {
        const float bv = bias[wave * 16 + l15];
        const __half* Bb = Wf + (size_t)(wave * 16 + l15) * KPAD + l4 * 8;
        f16x8 bfrag[10];
        #pragma unroll
        for (int kk = 0; kk < 10; ++kk)
            bfrag[kk] = *(const f16x8*)(Bb + kk * 32);
        const int moff[4] = {0, 16, 32, 44};
        #pragma unroll
        for (int mi = 0; mi < 4; ++mi) {
            const char* Ab = (const char*)ys + (moff[mi] + l15) * 656 + l4 * 16;
            f32x4 acc = f32x4{bv, bv, bv, bv};
            #pragma unroll
            for (int kk = 0; kk < 10; ++kk) {
                f16x8 af = *(const f16x8*)(Ab + kk * 64);
                acc = __builtin_amdgcn_mfma_f32_16x16x32_f16(af, bfrag[kk], acc, 0, 0, 0);
            }
            const int tg = t0 + moff[mi] + l4 * 4;   // row = l4*4 + reg -> t
            float* op = out + ((size_t)(n * O_DIM + wave * 16 + l15) * J_DIM + j) * T_DIM + tg;
            *(f32x4*)op = acc;
        }
    }
}

extern "C" void kernel_launch(void* const* d_in, const int* in_sizes, int n_in,
                              void* d_out, int out_size, void* d_ws, size_t ws_size,
                              hipStream_t stream) {
    const float* x = (const float*)d_in[0];
    const float* W = (const float*)d_in[1];
    const float* b = (const float*)d_in[2];
    float* out = (float*)d_out;
    __half* Wf = (__half*)d_ws;                  // 64*328*2 = 41,984 B

    wprep<<<(O_DIM * KPAD + 255) / 256, 256, 0, stream>>>(W, Wf);
    sig_mfma<<<64 * J_DIM * 2, 256, 0, stream>>>(x, Wf, b, out);
}

// Round 30
// 33.043 us; speedup vs baseline: 1.0612x; 1.0612x over previous
//
#include <hip/hip_runtime.h>
#include <hip/hip_fp16.h>

#define J_DIM 25
#define T_DIM 120
#define O_DIM 64
#define KPAD  328        // f16 per ys/Wf row; 656 B = 41*16 (b128-aligned)
#define TB    64         // t-rows per block; chunks t0 = 0, 56 (8 dup rows, benign)
#define XPADH 24         // xs row pad (halves): 48 B rows -> 16-B aligned

typedef _Float16 f16x8 __attribute__((ext_vector_type(8)));
typedef __attribute__((ext_vector_type(4))) float f32x4;

__device__ __forceinline__ unsigned h2bits(__half2 h) {
    unsigned u; __builtin_memcpy(&u, &h, 4); return u;
}
__device__ __forceinline__ __half2 bits2h(unsigned u) {
    __half2 h; __builtin_memcpy(&h, &u, 4); return h;
}
// select one of 4 half2 by q (0..3): 3 v_cndmask, no LDS, no runtime reg-indexing
__device__ __forceinline__ __half2 sel4h(int q, __half2 a, __half2 b, __half2 c, __half2 d) {
    unsigned s01 = (q & 1) ? h2bits(b) : h2bits(a);
    unsigned s23 = (q & 1) ? h2bits(d) : h2bits(c);
    return bits2h((q & 2) ? s23 : s01);
}

// ---- W (306x64 f32) -> Wf[o][k] f16, k = 18a+b; b<17: 0.5*W2[a,b]; b==17: W1[a] ----
__global__ void wprep(const float* __restrict__ W, __half* __restrict__ Wf) {
    int i = blockIdx.x * 256 + threadIdx.x;
    if (i >= O_DIM * KPAD) return;
    int o = i / KPAD, k = i % KPAD;
    int a = k / 18, b = k % 18;
    float v = 0.0f;
    if (k < 306) v = (b == 17) ? W[a * O_DIM + o] : 0.5f * W[(17 + 17 * a + b) * O_DIM + o];
    Wf[o * KPAD + k] = __float2half(v);
}

// ---- main: block = (n, j, 64-row half); 256 threads; SINGLE block barrier ----
// R25/R28 exact (session best, 33.14-33.19 us, twice reproduced): wave-local
// stage + phase-1 (wave_barrier only), one __syncthreads, phase 2 o-quarter
// with bfrag[10] register reuse.
// Lessons: no launch_bounds clamp (R6/R10); flat straight-line phases
// (R8/R9/R13); no runtime reg-array indexing (rule #20); bfrag reuse is
// load-bearing (R24/R26); TB=60 zero-dup tiling regressed (R29); R27
// micro-opts neutral -> not carried.
__global__ __launch_bounds__(256, 2) void sig_mfma(
    const float* __restrict__ x, const __half* __restrict__ Wf,
    const float* __restrict__ bias, float* __restrict__ out)
{
    __shared__ __half xs[4][20][XPADH];          // 3,840 B (per-wave 20-row slices)
    __shared__ __half ys[TB * KPAD];             // 41,984 B  (total 45.8 KB -> 3 blk/CU)

    const int tid = threadIdx.x;
    const int bid = blockIdx.x;
    const int half_ = bid & 1;
    const int j = (bid >> 1) % J_DIM;
    const int n = bid / (2 * J_DIM);
    const int t0 = half_ * 56;                   // halves overlap rows 56..63 (dup stores)
    const int wave = tid >> 6, lane = tid & 63;
    const int l15 = lane & 15, l4 = lane >> 4;
    const int t0w = t0 + wave * 16;              // this wave's first t-row

    // ---- wave-local stage: xs[wave][i][c] = f16 x[n,c,j,clamp(t0w-2+i)] ----
    const float* xbase = x + ((size_t)(n * 16) * J_DIM + j) * T_DIM;
    #pragma unroll
    for (int k = 0; k < 5; ++k) {
        int idx = lane + k * 64;                 // 0..319 = 16 ch x 20 rows
        int c = idx / 20, i = idx % 20;
        int st = min(max(t0w - 2 + i, 0), T_DIM - 1);
        xs[wave][i][c] = __float2half(xbase[(size_t)c * J_DIM * T_DIM + st]);
    }
    // wave-local zero of this wave's 16 rows' pad bytes [608,656)
    // ([608,612) re-written below by the same wave's time-row store: DS in-order)
    if (lane < 48) {
        int r = lane / 3, p = lane % 3;
        *(uint4*)((char*)ys + (wave * 16 + r) * 656 + 608 + p * 16) = uint4{0, 0, 0, 0};
    }
    __builtin_amdgcn_wave_barrier();             // program-order pin (no runtime cost)

    // ---- phase 1: thread = (row = tid>>2, qg = tid&3); q = qg and qg+4, SAME row ----
    // S2[a,b] = sum_w h_w[a]*p_w[b], h = (-p1, p0-p2, p1-p3, p2-p4, p3+p4)
    {
        const int row = tid >> 2, qg = tid & 3;  // row = wave*16 + (lane>>2)
        const int rloc = lane >> 2;              // row within wave slice
        const int t = t0 + row;
        const int start = max(t - 2, 0), end = min(t + 3, T_DIM);
        const float inv = 1.0f / (float)(end - start - 1);
        float ptvf[5];
        #pragma unroll
        for (int w = 0; w < 5; ++w) {
            int pcw = min(max(t - 2 + w, 0), T_DIM - 1);
            ptvf[w] = (float)(pcw - start) * inv;
        }
        __half2 ptvb[5];
        #pragma unroll
        for (int w = 0; w < 5; ++w) ptvb[w] = __float2half2_rn(ptvf[w]);

        // full 16-channel window: 2 x uint4 (b128) per row, unpack to half2 regs
        __half2 xw[5][8];
        #pragma unroll
        for (int w = 0; w < 5; ++w) {
            uint4 lo = *(const uint4*)&xs[wave][rloc + w][0];
            uint4 hi = *(const uint4*)&xs[wave][rloc + w][8];
            xw[w][0] = bits2h(lo.x); xw[w][1] = bits2h(lo.y);
            xw[w][2] = bits2h(lo.z); xw[w][3] = bits2h(lo.w);
            xw[w][4] = bits2h(hi.x); xw[w][5] = bits2h(hi.y);
            xw[w][6] = bits2h(hi.z); xw[w][7] = bits2h(hi.w);
        }

        // ---------- A-pair: q = qg, a-rows {2qg, 2qg+1} ----------
        {
            __half2 pr[5];
            #pragma unroll
            for (int w = 0; w < 5; ++w)
                pr[w] = sel4h(qg, xw[w][0], xw[w][1], xw[w][2], xw[w][3]);
            __half2 hp[5];
            hp[0] = __hneg2(pr[1]);
            hp[1] = __hsub2(pr[0], pr[2]);
            hp[2] = __hsub2(pr[1], pr[3]);
            hp[3] = __hsub2(pr[2], pr[4]);
            hp[4] = __hadd2(pr[3], pr[4]);
            __half2 h0b[5], h1b[5];
            #pragma unroll
            for (int w = 0; w < 5; ++w) {
                h0b[w] = __low2half2(hp[w]);
                h1b[w] = __high2half2(hp[w]);
            }
            unsigned u0[9], u1[9];
            #pragma unroll
            for (int b2 = 0; b2 < 8; ++b2) {
                __half2 a0 = __hmul2(h0b[0], xw[0][b2]);
                __half2 a1 = __hmul2(h1b[0], xw[0][b2]);
                #pragma unroll
                for (int w = 1; w < 5; ++w) {
                    a0 = __hfma2(h0b[w], xw[w][b2], a0);
                    a1 = __hfma2(h1b[w], xw[w][b2], a1);
                }
                u0[b2] = h2bits(a0);
                u1[b2] = h2bits(a1);
            }
            {   // b-pair (16,17): {S2[a,16], S1[a]=p4[a]}
                __half2 a16 = __hmul2(hp[0], ptvb[0]);
                #pragma unroll
                for (int w = 1; w < 5; ++w) a16 = __hfma2(hp[w], ptvb[w], a16);
                u0[8] = h2bits(__halves2half2(__low2half(a16),  __low2half(pr[4])));
                u1[8] = h2bits(__halves2half2(__high2half(a16), __high2half(pr[4])));
            }
            char* yr = (char*)ys + row * 656 + 72 * qg;      // rows 2qg,2qg+1
            *(uint2*)(yr +  0) = uint2{u0[0], u0[1]};
            *(uint2*)(yr +  8) = uint2{u0[2], u0[3]};
            *(uint2*)(yr + 16) = uint2{u0[4], u0[5]};
            *(uint2*)(yr + 24) = uint2{u0[6], u0[7]};
            *(uint2*)(yr + 32) = uint2{u0[8], u1[0]};
            *(uint2*)(yr + 40) = uint2{u1[1], u1[2]};
            *(uint2*)(yr + 48) = uint2{u1[3], u1[4]};
            *(uint2*)(yr + 56) = uint2{u1[5], u1[6]};
            *(uint2*)(yr + 64) = uint2{u1[7], u1[8]};
        }

        // ---------- B-pair: q = qg+4, a-rows {2qg+8, 2qg+9} ----------
        {
            __half2 pr[5];
            #pragma unroll
            for (int w = 0; w < 5; ++w)
                pr[w] = sel4h(qg, xw[w][4], xw[w][5], xw[w][6], xw[w][7]);
            __half2 hp[5];
            hp[0] = __hneg2(pr[1]);
            hp[1] = __hsub2(pr[0], pr[2]);
            hp[2] = __hsub2(pr[1], pr[3]);
            hp[3] = __hsub2(pr[2], pr[4]);
            hp[4] = __hadd2(pr[3], pr[4]);
            __half2 h0b[5], h1b[5];
            #pragma unroll
            for (int w = 0; w < 5; ++w) {
                h0b[w] = __low2half2(hp[w]);
                h1b[w] = __high2half2(hp[w]);
            }
            unsigned u0[9], u1[9];
            #pragma unroll
            for (int b2 = 0; b2 < 8; ++b2) {
                __half2 a0 = __hmul2(h0b[0], xw[0][b2]);
                __half2 a1 = __hmul2(h1b[0], xw[0][b2]);
                #pragma unroll
                for (int w = 1; w < 5; ++w) {
                    a0 = __hfma2(h0b[w], xw[w][b2], a0);
                    a1 = __hfma2(h1b[w], xw[w][b2], a1);
                }
                u0[b2] = h2bits(a0);
                u1[b2] = h2bits(a1);
            }
            {   // b-pair (16,17)
                __half2 a16 = __hmul2(hp[0], ptvb[0]);
                #pragma unroll
                for (int w = 1; w < 5; ++w) a16 = __hfma2(hp[w], ptvb[w], a16);
                u0[8] = h2bits(__halves2half2(__low2half(a16),  __low2half(pr[4])));
                u1[8] = h2bits(__halves2half2(__high2half(a16), __high2half(pr[4])));
            }
            char* yr = (char*)ys + row * 656 + 72 * qg + 288;  // rows 2qg+8, 2qg+9
            *(uint2*)(yr +  0) = uint2{u0[0], u0[1]};
            *(uint2*)(yr +  8) = uint2{u0[2], u0[3]};
            *(uint2*)(yr + 16) = uint2{u0[4], u0[5]};
            *(uint2*)(yr + 24) = uint2{u0[6], u0[7]};
            *(uint2*)(yr + 32) = uint2{u0[8], u1[0]};
            *(uint2*)(yr + 40) = uint2{u1[1], u1[2]};
            *(uint2*)(yr + 48) = uint2{u1[3], u1[4]};
            *(uint2*)(yr + 56) = uint2{u1[5], u1[6]};
            *(uint2*)(yr + 64) = uint2{u1[7], u1[8]};
        }

        // ---------- time row a=16 (once per row, qg==0; same wave as pad-zero) ----------
        if (qg == 0) {
            __half2 htb[5];
            htb[0] = __float2half2_rn(-ptvf[1]);
            htb[1] = __float2half2_rn(ptvf[0] - ptvf[2]);
            htb[2] = __float2half2_rn(ptvf[1] - ptvf[3]);
            htb[3] = __float2half2_rn(ptvf[2] - ptvf[4]);
            htb[4] = __float2half2_rn(ptvf[3] + ptvf[4]);
            unsigned ut[9];
            #pragma unroll
            for (int b2 = 0; b2 < 8; ++b2) {
                __half2 a = __hmul2(htb[0], xw[0][b2]);
                #pragma unroll
                for (int w = 1; w < 5; ++w) a = __hfma2(htb[w], xw[w][b2], a);
                ut[b2] = h2bits(a);
            }
            {   // {S2[16,16], S1[16]=ptv4}
                __half2 a = __hmul2(htb[0], ptvb[0]);
                #pragma unroll
                for (int w = 1; w < 5; ++w) a = __hfma2(htb[w], ptvb[w], a);
                ut[8] = h2bits(__halves2half2(__low2half(a), __float2half(ptvf[4])));
            }
            char* yt = (char*)ys + row * 656 + 576;          // bytes [576,612)
            *(uint2*)(yt +  0) = uint2{ut[0], ut[1]};
            *(uint2*)(yt +  8) = uint2{ut[2], ut[3]};
            *(uint2*)(yt + 16) = uint2{ut[4], ut[5]};
            *(uint2*)(yt + 24) = uint2{ut[6], ut[7]};
            *(unsigned*)(yt + 32) = ut[8];
        }
    }
    __syncthreads();    // the ONLY block barrier: ys complete -> phase 2

    // ---- phase 2: wave = o-quarter; B-frags loaded once, reused over 4 M-tiles ----
    {
        const float bv = bias[wave * 16 + l15];
        const __half* Bb = Wf + (size_t)(wave * 16 + l15) * KPAD + l4 * 8;
        f16x8 bfrag[10];
        #pragma unroll
        for (int kk = 0; kk < 10; ++kk)
            bfrag[kk] = *(const f16x8*)(Bb + kk * 32);
        #pragma unroll
        for (int mi = 0; mi < 4; ++mi) {
            const char* Ab = (const char*)ys + (mi * 16 + l15) * 656 + l4 * 16;
            f32x4 acc = f32x4{bv, bv, bv, bv};
            #pragma unroll
            for (int kk = 0; kk < 10; ++kk) {
                f16x8 af = *(const f16x8*)(Ab + kk * 64);
                acc = __builtin_amdgcn_mfma_f32_16x16x32_f16(af, bfrag[kk], acc, 0, 0, 0);
            }
            const int tg = t0 + mi * 16 + l4 * 4;    // row = l4*4 + reg -> t
            float* op = out + ((size_t)(n * O_DIM + wave * 16 + l15) * J_DIM + j) * T_DIM + tg;
            *(f32x4*)op = acc;
        }
    }
}

extern "C" void kernel_launch(void* const* d_in, const int* in_sizes, int n_in,
                              void* d_out, int out_size, void* d_ws, size_t ws_size,
                              hipStream_t stream) {
    const float* x = (const float*)d_in[0];
    const float* W = (const float*)d_in[1];
    const float* b = (const float*)d_in[2];
    float* out = (float*)d_out;
    __half* Wf = (__half*)d_ws;                  // 64*328*2 = 41,984 B

    wprep<<<(O_DIM * KPAD + 255) / 256, 256, 0, stream>>>(W, Wf);
    sig_mfma<<<64 * J_DIM * 2, 256, 0, stream>>>(x, Wf, b, out);
}